// Round 2
// baseline (96.022 us; speedup 1.0000x reference)
//
#include <hip/hip_runtime.h>
#include <hip/hip_bf16.h>

typedef __attribute__((ext_vector_type(8))) short bf16x8;
typedef __attribute__((ext_vector_type(4))) float f32x4;

__device__ __forceinline__ unsigned short f2bf(float f) {
  unsigned int u = __float_as_uint(f);
  u += 0x7FFFu + ((u >> 16) & 1u);   // round-to-nearest-even
  return (unsigned short)(u >> 16);
}

// qw[n][e] = scale * sum_d query[n][d] * W[d][e]   (N=64, E=256), stored bf16
__global__ void __launch_bounds__(256) qw_kernel(const float* __restrict__ q,
                                                 const float* __restrict__ W,
                                                 unsigned short* __restrict__ qw) {
  int n = blockIdx.x, e = threadIdx.x;
  float acc = 0.f;
  #pragma unroll 8
  for (int d = 0; d < 256; ++d) acc = fmaf(q[n * 256 + d], W[d * 256 + e], acc);
  qw[n * 256 + e] = f2bf(acc * 0.0625f);  // scale = 256^-0.5
}

// One block per batch b. 512 threads = 8 waves.
// Phases: stage x -> att^T GEMM (MFMA) -> entmax15 -> out GEMM (MFMA) + exp
__global__ void __launch_bounds__(512, 4) cross_main(
    const float* __restrict__ x, const float* __restrict__ value,
    const unsigned short* __restrict__ qw, float* __restrict__ out) {

  __shared__ __align__(16) unsigned short lds_x[64 * 264];  // x[f][e] bf16, stride 264
  __shared__ __align__(16) unsigned short lds_aw[64 * 72];  // aw[n][f] bf16, stride 72
  __shared__ __align__(16) float lds_att[64 * 68];          // att[n][f] f32, stride 68

  const int t = threadIdx.x;
  const int b = blockIdx.x;
  const int l = t & 63;
  const int w = t >> 6;
  const int l15 = l & 15, l4 = l >> 4;

  // ---- stage x[b] (fp32 global) -> bf16 LDS ----
  {
    const float4* xg = (const float4*)(x + (size_t)b * 16384);
    #pragma unroll
    for (int it = 0; it < 8; ++it) {
      int i = it * 512 + t;          // float4 chunk id 0..4095
      float4 v = xg[i];
      int f = i >> 6, c = i & 63;    // row f, 4-elem chunk c
      unsigned int lo = (unsigned int)f2bf(v.x) | ((unsigned int)f2bf(v.y) << 16);
      unsigned int hi = (unsigned int)f2bf(v.z) | ((unsigned int)f2bf(v.w) << 16);
      *(uint2*)&lds_x[f * 264 + 4 * c] = make_uint2(lo, hi);
    }
  }
  __syncthreads();

  // ---- att[n][f] = sum_e qw[n][e] * x[f][e]  (D = qw · x^T, M=n, N=f, K=e) ----
  {
    int nt = w >> 1, ft0 = (w & 1) * 2;    // wave tile: 1 n-tile x 2 f-tiles
    f32x4 acc0 = {0.f, 0.f, 0.f, 0.f}, acc1 = {0.f, 0.f, 0.f, 0.f};
    const unsigned short* qa = qw + (nt * 16 + l15) * 256 + l4 * 8;
    const unsigned short* xb0 = &lds_x[(ft0 * 16 + l15) * 264 + l4 * 8];
    const unsigned short* xb1 = xb0 + 16 * 264;
    #pragma unroll
    for (int kc = 0; kc < 8; ++kc) {
      bf16x8 a  = *(const bf16x8*)(qa + kc * 32);    // global (L2-resident)
      bf16x8 b0 = *(const bf16x8*)(xb0 + kc * 32);   // LDS b128
      bf16x8 b1 = *(const bf16x8*)(xb1 + kc * 32);
      acc0 = __builtin_amdgcn_mfma_f32_16x16x32_bf16(a, b0, acc0, 0, 0, 0);
      acc1 = __builtin_amdgcn_mfma_f32_16x16x32_bf16(a, b1, acc1, 0, 0, 0);
    }
    int nrow = nt * 16 + 4 * l4;
    #pragma unroll
    for (int r = 0; r < 4; ++r) {
      lds_att[(nrow + r) * 68 + ft0 * 16 + l15]       = acc0[r];
      lds_att[(nrow + r) * 68 + (ft0 + 1) * 16 + l15] = acc1[r];
    }
  }
  __syncthreads();

  // ---- entmax15 over f per (n) row; aw[n][f] = gate * value[n][f] ----
  {
    int n = w * 8 + (l >> 3);       // 8-lane group per row
    int fb = (l & 7) * 8;           // 8 f's per lane
    f32x4 z0 = *(const f32x4*)&lds_att[n * 68 + fb];
    f32x4 z1 = *(const f32x4*)&lds_att[n * 68 + fb + 4];
    float z[8];
    #pragma unroll
    for (int k = 0; k < 4; ++k) { z[k] = z0[k] * 0.5f; z[k + 4] = z1[k] * 0.5f; }
    float m = z[0];
    #pragma unroll
    for (int k = 1; k < 8; ++k) m = fmaxf(m, z[k]);
    m = fmaxf(m, __shfl_xor(m, 1));
    m = fmaxf(m, __shfl_xor(m, 2));
    m = fmaxf(m, __shfl_xor(m, 4));
    float tau = m - 1.0f;                 // gp(1, 1.5)
    float dm = (m - 0.125f) - tau;        // tau_hi - tau_lo, (1/64)^0.5 = 0.125
    float s = 0.f;
    #pragma unroll
    for (int k = 0; k < 8; ++k) { float d = fmaxf(z[k] - tau, 0.f); s = fmaf(d, d, s); }
    s += __shfl_xor(s, 1); s += __shfl_xor(s, 2); s += __shfl_xor(s, 4);
    const float f_lo = s - 1.0f;
    for (int it = 0; it < 40; ++it) {     // iters >~30 change tau < 1e-12: inert
      dm *= 0.5f;
      float tm = tau + dm;
      float s2 = 0.f;
      #pragma unroll
      for (int k = 0; k < 8; ++k) { float d = fmaxf(z[k] - tm, 0.f); s2 = fmaf(d, d, s2); }
      s2 += __shfl_xor(s2, 1); s2 += __shfl_xor(s2, 2); s2 += __shfl_xor(s2, 4);
      if ((s2 - 1.0f) * f_lo >= 0.f) tau = tm;
    }
    float p[8]; float S = 0.f;
    #pragma unroll
    for (int k = 0; k < 8; ++k) { float d = fmaxf(z[k] - tau, 0.f); p[k] = d * d; S += p[k]; }
    S += __shfl_xor(S, 1); S += __shfl_xor(S, 2); S += __shfl_xor(S, 4);
    float invS = 1.0f / S;
    const float4* vg = (const float4*)(value + n * 64 + fb);
    float4 va = vg[0], vb = vg[1];
    union { unsigned short u[8]; bf16x8 v; } pk;
    pk.u[0] = f2bf(p[0] * invS * va.x); pk.u[1] = f2bf(p[1] * invS * va.y);
    pk.u[2] = f2bf(p[2] * invS * va.z); pk.u[3] = f2bf(p[3] * invS * va.w);
    pk.u[4] = f2bf(p[4] * invS * vb.x); pk.u[5] = f2bf(p[5] * invS * vb.y);
    pk.u[6] = f2bf(p[6] * invS * vb.z); pk.u[7] = f2bf(p[7] * invS * vb.w);
    *(bf16x8*)&lds_aw[n * 72 + fb] = pk.v;
  }
  __syncthreads();

  // ---- out[n][e] = exp( sum_f aw[n][f] * x[f][e] )  (M=n, N=e, K=f) ----
  {
    int nt = w >> 1, et0 = (w & 1) * 8;   // wave tile: 1 n-tile x 8 e-tiles
    f32x4 acc[8];
    #pragma unroll
    for (int j = 0; j < 8; ++j) acc[j] = (f32x4){0.f, 0.f, 0.f, 0.f};
    #pragma unroll
    for (int kc = 0; kc < 2; ++kc) {
      bf16x8 a = *(const bf16x8*)&lds_aw[(nt * 16 + l15) * 72 + kc * 32 + l4 * 8];
      int f0 = kc * 32 + l4 * 8;
      #pragma unroll
      for (int j = 0; j < 8; ++j) {
        int e = (et0 + j) * 16 + l15;
        union { unsigned short u[8]; bf16x8 v; } bb;   // transposed gather of x
        #pragma unroll
        for (int i = 0; i < 8; ++i) bb.u[i] = lds_x[(f0 + i) * 264 + e];
        acc[j] = __builtin_amdgcn_mfma_f32_16x16x32_bf16(a, bb.v, acc[j], 0, 0, 0);
      }
    }
    float* ob = out + (size_t)b * 16384;
    int nbase = nt * 16 + 4 * l4;
    #pragma unroll
    for (int j = 0; j < 8; ++j) {
      #pragma unroll
      for (int r = 0; r < 4; ++r) {
        ob[(nbase + r) * 256 + (et0 + j) * 16 + l15] = __expf(acc[j][r]);
      }
    }
  }
}

extern "C" void kernel_launch(void* const* d_in, const int* in_sizes, int n_in,
                              void* d_out, int out_size, void* d_ws, size_t ws_size,
                              hipStream_t stream) {
  const float* x     = (const float*)d_in[0];
  const float* W     = (const float*)d_in[1];
  const float* q     = (const float*)d_in[2];
  const float* value = (const float*)d_in[3];
  float* out = (float*)d_out;
  unsigned short* qw = (unsigned short*)d_ws;  // 64*256 bf16 = 32 KB scratch

  qw_kernel<<<dim3(64), dim3(256), 0, stream>>>(q, W, qw);
  cross_main<<<dim3(2048), dim3(512), 0, stream>>>(x, value, qw, out);
}

// Round 4
// 76.919 us; speedup vs baseline: 1.2484x; 1.2484x over previous
//
#include <hip/hip_runtime.h>
#include <hip/hip_bf16.h>

typedef __attribute__((ext_vector_type(8))) short bf16x8;
typedef __attribute__((ext_vector_type(4))) float f32x4;

__device__ __forceinline__ unsigned short f2bf(float f) {
  unsigned int u = __float_as_uint(f);
  u += 0x7FFFu + ((u >> 16) & 1u);   // round-to-nearest-even
  return (unsigned short)(u >> 16);
}

// qw[n][e] = scale * sum_d query[n][d] * W[d][e]   (N=64, E=256), stored bf16
__global__ void __launch_bounds__(256) qw_kernel(const float* __restrict__ q,
                                                 const float* __restrict__ W,
                                                 unsigned short* __restrict__ qw) {
  int n = blockIdx.x, e = threadIdx.x;
  float acc = 0.f;
  #pragma unroll 8
  for (int d = 0; d < 256; ++d) acc = fmaf(q[n * 256 + d], W[d * 256 + e], acc);
  qw[n * 256 + e] = f2bf(acc * 0.0625f);  // scale = 256^-0.5
}

// One block per batch b. 512 threads = 8 waves.
// R4: round-2 datapath (linear lds_x, u16-gather GEMM2 B) + GEMM2 retile
//     (4 n-tiles x 2 private e-tiles per wave) + att/aw LDS overlay + 28 iters.
__global__ void __launch_bounds__(512, 6) cross_main(
    const float* __restrict__ x, const float* __restrict__ value,
    const unsigned short* __restrict__ qw, float* __restrict__ out) {

  __shared__ __align__(16) unsigned short lds_x[64 * 264];       // 33 KB, x[f][e] bf16, stride 264
  __shared__ __align__(16) unsigned char  lds_pool[64 * 68 * 4]; // 17 KB: att (f32) then aw (bf16)

  float* lds_att = (float*)lds_pool;                  // [64][68] f32: GEMM1 -> entmax load
  unsigned short* lds_aw = (unsigned short*)lds_pool; // [64][72] bf16: entmax store -> GEMM2

  const int t = threadIdx.x;
  const int b = blockIdx.x;
  const int l = t & 63;
  const int w = t >> 6;
  const int l15 = l & 15, l4 = l >> 4;

  // ---- stage x[b] (fp32 global) -> bf16 LDS ----
  {
    const float4* xg = (const float4*)(x + (size_t)b * 16384);
    #pragma unroll
    for (int it = 0; it < 8; ++it) {
      int i = it * 512 + t;          // float4 chunk id 0..4095
      float4 v = xg[i];
      int f = i >> 6, c = i & 63;    // row f, 4-elem chunk c
      unsigned int lo = (unsigned int)f2bf(v.x) | ((unsigned int)f2bf(v.y) << 16);
      unsigned int hi = (unsigned int)f2bf(v.z) | ((unsigned int)f2bf(v.w) << 16);
      *(uint2*)&lds_x[f * 264 + 4 * c] = make_uint2(lo, hi);
    }
  }
  __syncthreads();

  // ---- att[n][f] = sum_e qw[n][e] * x[f][e]  (M=n, N=f, K=e) ----
  {
    int nt = w >> 1, ft0 = (w & 1) * 2;    // wave tile: 1 n-tile x 2 f-tiles
    f32x4 acc0 = {0.f, 0.f, 0.f, 0.f}, acc1 = {0.f, 0.f, 0.f, 0.f};
    const unsigned short* qa = qw + (nt * 16 + l15) * 256 + l4 * 8;
    const unsigned short* xb0 = &lds_x[(ft0 * 16 + l15) * 264 + l4 * 8];
    const unsigned short* xb1 = xb0 + 16 * 264;
    #pragma unroll
    for (int kc = 0; kc < 8; ++kc) {
      bf16x8 a  = *(const bf16x8*)(qa + kc * 32);    // global (L1/L2-resident)
      bf16x8 b0 = *(const bf16x8*)(xb0 + kc * 32);   // LDS b128
      bf16x8 b1 = *(const bf16x8*)(xb1 + kc * 32);
      acc0 = __builtin_amdgcn_mfma_f32_16x16x32_bf16(a, b0, acc0, 0, 0, 0);
      acc1 = __builtin_amdgcn_mfma_f32_16x16x32_bf16(a, b1, acc1, 0, 0, 0);
    }
    int nrow = nt * 16 + 4 * l4;
    #pragma unroll
    for (int r = 0; r < 4; ++r) {
      lds_att[(nrow + r) * 68 + ft0 * 16 + l15]       = acc0[r];
      lds_att[(nrow + r) * 68 + (ft0 + 1) * 16 + l15] = acc1[r];
    }
  }
  __syncthreads();

  // ---- entmax15 over f per (n) row; aw[n][f] = gate * value[n][f] ----
  {
    int n = w * 8 + (l >> 3);       // 8-lane group per row
    int fb = (l & 7) * 8;           // 8 f's per lane
    f32x4 z0 = *(const f32x4*)&lds_att[n * 68 + fb];
    f32x4 z1 = *(const f32x4*)&lds_att[n * 68 + fb + 4];
    __syncthreads();                // att dead after this barrier; aw may overwrite pool
    float z[8];
    #pragma unroll
    for (int k = 0; k < 4; ++k) { z[k] = z0[k] * 0.5f; z[k + 4] = z1[k] * 0.5f; }
    float m = z[0];
    #pragma unroll
    for (int k = 1; k < 8; ++k) m = fmaxf(m, z[k]);
    m = fmaxf(m, __shfl_xor(m, 1));
    m = fmaxf(m, __shfl_xor(m, 2));
    m = fmaxf(m, __shfl_xor(m, 4));
    float tau = m - 1.0f;                 // gp(1, 1.5)
    float dm = (m - 0.125f) - tau;        // tau_hi - tau_lo, (1/64)^0.5 = 0.125
    float s = 0.f;
    #pragma unroll
    for (int k = 0; k < 8; ++k) { float d = fmaxf(z[k] - tau, 0.f); s = fmaf(d, d, s); }
    s += __shfl_xor(s, 1); s += __shfl_xor(s, 2); s += __shfl_xor(s, 4);
    const float f_lo = s - 1.0f;
    for (int it = 0; it < 28; ++it) {     // f32 fixed point by ~24 iters (validated 40 vs ref 50)
      dm *= 0.5f;
      float tm = tau + dm;
      float s2 = 0.f;
      #pragma unroll
      for (int k = 0; k < 8; ++k) { float d = fmaxf(z[k] - tm, 0.f); s2 = fmaf(d, d, s2); }
      s2 += __shfl_xor(s2, 1); s2 += __shfl_xor(s2, 2); s2 += __shfl_xor(s2, 4);
      if ((s2 - 1.0f) * f_lo >= 0.f) tau = tm;
    }
    float p[8]; float S = 0.f;
    #pragma unroll
    for (int k = 0; k < 8; ++k) { float d = fmaxf(z[k] - tau, 0.f); p[k] = d * d; S += p[k]; }
    S += __shfl_xor(S, 1); S += __shfl_xor(S, 2); S += __shfl_xor(S, 4);
    float invS = 1.0f / S;
    const float4* vg = (const float4*)(value + n * 64 + fb);
    float4 va = vg[0], vb = vg[1];
    union { unsigned short u[8]; bf16x8 v; } pk;
    pk.u[0] = f2bf(p[0] * invS * va.x); pk.u[1] = f2bf(p[1] * invS * va.y);
    pk.u[2] = f2bf(p[2] * invS * va.z); pk.u[3] = f2bf(p[3] * invS * va.w);
    pk.u[4] = f2bf(p[4] * invS * vb.x); pk.u[5] = f2bf(p[5] * invS * vb.y);
    pk.u[6] = f2bf(p[6] * invS * vb.z); pk.u[7] = f2bf(p[7] * invS * vb.w);
    *(bf16x8*)&lds_aw[n * 72 + fb] = pk.v;
  }
  __syncthreads();

  // ---- out[n][e] = exp( sum_f aw[n][f] * x[f][e] )  (M=n, N=e, K=f) ----
  // Wave w owns e-tiles {2w, 2w+1} and ALL 4 n-tiles: no B-fragment redundancy,
  // 32 u16 gathers per thread (vs 128 in round 2).
  {
    const int te0 = 2 * w;
    f32x4 acc[4][2];
    #pragma unroll
    for (int nt = 0; nt < 4; ++nt) {
      acc[nt][0] = (f32x4){0.f, 0.f, 0.f, 0.f};
      acc[nt][1] = (f32x4){0.f, 0.f, 0.f, 0.f};
    }
    #pragma unroll
    for (int kc = 0; kc < 2; ++kc) {
      bf16x8 a[4];
      #pragma unroll
      for (int nt = 0; nt < 4; ++nt)
        a[nt] = *(const bf16x8*)&lds_aw[(nt * 16 + l15) * 72 + kc * 32 + l4 * 8];
      int f0 = kc * 32 + l4 * 8;
      #pragma unroll
      for (int j = 0; j < 2; ++j) {
        int e = (te0 + j) * 16 + l15;
        union { unsigned short u[8]; bf16x8 v; } bb;   // transposed gather of x
        #pragma unroll
        for (int i = 0; i < 8; ++i) bb.u[i] = lds_x[(f0 + i) * 264 + e];
        #pragma unroll
        for (int nt = 0; nt < 4; ++nt)
          acc[nt][j] = __builtin_amdgcn_mfma_f32_16x16x32_bf16(a[nt], bb.v, acc[nt][j], 0, 0, 0);
      }
    }
    float* ob = out + (size_t)b * 16384;
    #pragma unroll
    for (int nt = 0; nt < 4; ++nt) {
      #pragma unroll
      for (int j = 0; j < 2; ++j) {
        #pragma unroll
        for (int r = 0; r < 4; ++r) {
          ob[(nt * 16 + 4 * l4 + r) * 256 + (te0 + j) * 16 + l15] = __expf(acc[nt][j][r]);
        }
      }
    }
  }
}

extern "C" void kernel_launch(void* const* d_in, const int* in_sizes, int n_in,
                              void* d_out, int out_size, void* d_ws, size_t ws_size,
                              hipStream_t stream) {
  const float* x     = (const float*)d_in[0];
  const float* W     = (const float*)d_in[1];
  const float* q     = (const float*)d_in[2];
  const float* value = (const float*)d_in[3];
  float* out = (float*)d_out;
  unsigned short* qw = (unsigned short*)d_ws;  // 64*256 bf16 = 32 KB scratch

  qw_kernel<<<dim3(64), dim3(256), 0, stream>>>(q, W, qw);
  cross_main<<<dim3(2048), dim3(512), 0, stream>>>(x, value, qw, out);
}

// Round 5
// 71.521 us; speedup vs baseline: 1.3426x; 1.0755x over previous
//
#include <hip/hip_runtime.h>
#include <hip/hip_bf16.h>

typedef __attribute__((ext_vector_type(8))) short bf16x8;
typedef __attribute__((ext_vector_type(4))) float f32x4;

__device__ __forceinline__ unsigned int pk2(float a, float b) {
  union { __hip_bfloat162 h; unsigned int u; } cv;
  cv.h = __float22bfloat162_rn(make_float2(a, b));   // v_cvt_pk_bf16_f32
  return cv.u;
}
__device__ __forceinline__ unsigned short f2bf(float f) {
  unsigned int u = __float_as_uint(f);
  u += 0x7FFFu + ((u >> 16) & 1u);
  return (unsigned short)(u >> 16);
}

// qw[n][e] = scale * sum_d query[n][d] * W[d][e]   (N=64, E=256), stored bf16
__global__ void __launch_bounds__(256) qw_kernel(const float* __restrict__ q,
                                                 const float* __restrict__ W,
                                                 unsigned short* __restrict__ qw) {
  int n = blockIdx.x, e = threadIdx.x;
  float acc = 0.f;
  #pragma unroll 8
  for (int d = 0; d < 256; ++d) acc = fmaf(q[n * 256 + d], W[d * 256 + e], acc);
  qw[n * 256 + e] = f2bf(acc * 0.0625f);  // scale = 256^-0.5
}

// One block per batch b. 512 threads = 8 waves.
// R5: stride-268 lds_x (gather 4-way -> 2-way), cvt_pk conversions, Newton-12 entmax.
__global__ void __launch_bounds__(512, 6) cross_main(
    const float* __restrict__ x, const float* __restrict__ value,
    const unsigned short* __restrict__ qw, float* __restrict__ out) {

  __shared__ __align__(16) unsigned short lds_x[64 * 268];       // x[f][e] bf16, row = 536 B
  __shared__ __align__(16) unsigned char  lds_pool[64 * 68 * 4]; // att (f32) then aw (bf16)

  float* lds_att = (float*)lds_pool;                  // [64][68] f32: GEMM1 -> entmax
  unsigned short* lds_aw = (unsigned short*)lds_pool; // [64][72] bf16: entmax -> GEMM2

  const int t = threadIdx.x;
  const int b = blockIdx.x;
  const int l = t & 63;
  const int w = t >> 6;
  const int l15 = l & 15, l4 = l >> 4;

  // ---- stage x[b] (fp32 global) -> bf16 LDS via cvt_pk; 8 floats/thread/iter ----
  {
    const float4* xg = (const float4*)(x + (size_t)b * 16384);
    #pragma unroll
    for (int it = 0; it < 4; ++it) {
      int u = it * 512 + t;            // 8-float unit, 0..2047
      float4 v0 = xg[2 * u], v1 = xg[2 * u + 1];
      int f = u >> 5, c8 = u & 31;
      char* dst = (char*)lds_x + f * 536 + c8 * 16;   // 8-aligned
      *(uint2*)dst       = make_uint2(pk2(v0.x, v0.y), pk2(v0.z, v0.w));
      *(uint2*)(dst + 8) = make_uint2(pk2(v1.x, v1.y), pk2(v1.z, v1.w));
    }
  }
  __syncthreads();

  // ---- att[n][f] = sum_e qw[n][e] * x[f][e]  (M=n, N=f, K=e) ----
  {
    int nt = w >> 1, ft0 = (w & 1) * 2;    // wave tile: 1 n-tile x 2 f-tiles
    f32x4 acc0 = {0.f, 0.f, 0.f, 0.f}, acc1 = {0.f, 0.f, 0.f, 0.f};
    const unsigned short* qa = qw + (nt * 16 + l15) * 256 + l4 * 8;
    const char* rb0 = (const char*)lds_x + (ft0 * 16 + l15) * 536 + l4 * 16;
    const char* rb1 = rb0 + 16 * 536;
    #pragma unroll
    for (int kc = 0; kc < 8; ++kc) {
      union BF { uint2 d[2]; bf16x8 v; };
      bf16x8 a = *(const bf16x8*)(qa + kc * 32);       // global (L1/L2-resident)
      BF b0, b1;
      b0.d[0] = *(const uint2*)(rb0 + kc * 64);
      b0.d[1] = *(const uint2*)(rb0 + kc * 64 + 8);
      b1.d[0] = *(const uint2*)(rb1 + kc * 64);
      b1.d[1] = *(const uint2*)(rb1 + kc * 64 + 8);
      acc0 = __builtin_amdgcn_mfma_f32_16x16x32_bf16(a, b0.v, acc0, 0, 0, 0);
      acc1 = __builtin_amdgcn_mfma_f32_16x16x32_bf16(a, b1.v, acc1, 0, 0, 0);
    }
    int nrow = nt * 16 + 4 * l4;
    #pragma unroll
    for (int r = 0; r < 4; ++r) {
      lds_att[(nrow + r) * 68 + ft0 * 16 + l15]       = acc0[r];
      lds_att[(nrow + r) * 68 + (ft0 + 1) * 16 + l15] = acc1[r];
    }
  }
  __syncthreads();

  // ---- entmax15 over f per row (8 lanes/row); aw[n][f] = gate * value[n][f] ----
  {
    int n = w * 8 + (l >> 3);
    int fb = (l & 7) * 8;
    f32x4 z0 = *(const f32x4*)&lds_att[n * 68 + fb];
    f32x4 z1 = *(const f32x4*)&lds_att[n * 68 + fb + 4];
    __syncthreads();                // att dead; aw may overwrite pool
    float z[8];
    #pragma unroll
    for (int k = 0; k < 4; ++k) { z[k] = z0[k] * 0.5f; z[k + 4] = z1[k] * 0.5f; }
    float m = fmaxf(fmaxf(fmaxf(z[0], z[1]), fmaxf(z[2], z[3])),
                    fmaxf(fmaxf(z[4], z[5]), fmaxf(z[6], z[7])));
    m = fmaxf(m, __shfl_xor(m, 1));
    m = fmaxf(m, __shfl_xor(m, 2));
    m = fmaxf(m, __shfl_xor(m, 4));
    // Newton on f(tau) = sum (z-tau)_+^2 - 1: convex decreasing, start at bracket-lo
    // (f>=0) => monotone from below, quadratic endgame. 12 iters >> f32 fixed point.
    float tau = m - 1.0f;
    #pragma unroll
    for (int it = 0; it < 12; ++it) {
      float s0 = 0.f, s1 = 0.f, q0 = 0.f, q1 = 0.f;
      #pragma unroll
      for (int k = 0; k < 4; ++k) {
        float d0 = fmaxf(z[k] - tau, 0.f);
        float d1 = fmaxf(z[k + 4] - tau, 0.f);
        s0 = fmaf(d0, d0, s0); q0 += d0;
        s1 = fmaf(d1, d1, s1); q1 += d1;
      }
      float s = s0 + s1, q = q0 + q1;
      s += __shfl_xor(s, 1); s += __shfl_xor(s, 2); s += __shfl_xor(s, 4);
      q += __shfl_xor(q, 1); q += __shfl_xor(q, 2); q += __shfl_xor(q, 4);
      tau += (s - 1.0f) * 0.5f * __builtin_amdgcn_rcpf(q);
    }
    float p[8]; float S = 0.f;
    #pragma unroll
    for (int k = 0; k < 8; ++k) { float d = fmaxf(z[k] - tau, 0.f); p[k] = d * d; S += p[k]; }
    S += __shfl_xor(S, 1); S += __shfl_xor(S, 2); S += __shfl_xor(S, 4);
    float invS = 1.0f / S;
    const float4* vg = (const float4*)(value + n * 64 + fb);
    float4 va = vg[0], vb = vg[1];
    uint4 pkv;
    pkv.x = pk2(p[0] * invS * va.x, p[1] * invS * va.y);
    pkv.y = pk2(p[2] * invS * va.z, p[3] * invS * va.w);
    pkv.z = pk2(p[4] * invS * vb.x, p[5] * invS * vb.y);
    pkv.w = pk2(p[6] * invS * vb.z, p[7] * invS * vb.w);
    *(uint4*)&lds_aw[n * 72 + fb] = pkv;   // (n*72+fb)*2 is 16B-aligned
  }
  __syncthreads();

  // ---- out[n][e] = exp( sum_f aw[n][f] * x[f][e] )  (M=n, N=e, K=f) ----
  // Wave w owns e-tiles {2w,2w+1} and all 4 n-tiles; gather is 2-way (free) at stride 536.
  {
    const int te0 = 2 * w;
    f32x4 acc[4][2];
    #pragma unroll
    for (int nt = 0; nt < 4; ++nt) {
      acc[nt][0] = (f32x4){0.f, 0.f, 0.f, 0.f};
      acc[nt][1] = (f32x4){0.f, 0.f, 0.f, 0.f};
    }
    #pragma unroll
    for (int kc = 0; kc < 2; ++kc) {
      bf16x8 a[4];
      #pragma unroll
      for (int nt = 0; nt < 4; ++nt)
        a[nt] = *(const bf16x8*)&lds_aw[(nt * 16 + l15) * 72 + kc * 32 + l4 * 8];
      const char* gp = (const char*)lds_x + (kc * 32 + l4 * 8) * 536 + (te0 * 16 + l15) * 2;
      #pragma unroll
      for (int j = 0; j < 2; ++j) {
        union { unsigned short u[8]; bf16x8 v; } bb;   // transposed gather of x
        #pragma unroll
        for (int i = 0; i < 8; ++i)
          bb.u[i] = *(const unsigned short*)(gp + i * 536 + j * 32);
        #pragma unroll
        for (int nt = 0; nt < 4; ++nt)
          acc[nt][j] = __builtin_amdgcn_mfma_f32_16x16x32_bf16(a[nt], bb.v, acc[nt][j], 0, 0, 0);
      }
    }
    float* ob = out + (size_t)b * 16384;
    #pragma unroll
    for (int nt = 0; nt < 4; ++nt) {
      #pragma unroll
      for (int j = 0; j < 2; ++j) {
        #pragma unroll
        for (int r = 0; r < 4; ++r) {
          ob[(nt * 16 + 4 * l4 + r) * 256 + (te0 + j) * 16 + l15] = __expf(acc[nt][j][r]);
        }
      }
    }
  }
}

extern "C" void kernel_launch(void* const* d_in, const int* in_sizes, int n_in,
                              void* d_out, int out_size, void* d_ws, size_t ws_size,
                              hipStream_t stream) {
  const float* x     = (const float*)d_in[0];
  const float* W     = (const float*)d_in[1];
  const float* q     = (const float*)d_in[2];
  const float* value = (const float*)d_in[3];
  float* out = (float*)d_out;
  unsigned short* qw = (unsigned short*)d_ws;  // 64*256 bf16 = 32 KB scratch

  qw_kernel<<<dim3(64), dim3(256), 0, stream>>>(q, W, qw);
  cross_main<<<dim3(2048), dim3(512), 0, stream>>>(x, value, qw, out);
}